// Round 3
// baseline (16151.544 us; speedup 1.0000x reference)
//
#include <hip/hip_runtime.h>
#include <math.h>

// ---------------------------------------------------------------------------
// bert_output -> 2-layer BiLSTM -> FC -> CRF(loss) + Viterbi(tags)
// B=64 T=256 H=768 HH=384 K=9.  d_out is FLOAT32: [loss, tags(16384)].
// Windowed pipeline per layer: {gemm(win A); rec(128 steps); gemm(win B);
// rec(128 steps)} so the fp32 gate buffer is 2x50.3MB instead of 201MB.
// Layer 1's rec fuses the FC (em accumulation); fc bias added in crf_k.
// ---------------------------------------------------------------------------

#define TT 256
#define HID 768
#define HHD 384

// ======================= windowed input GEMM =======================
// Gf[b][tw][1536] <- X[b][t0f+tw] @ Wf^T + bias ; Gb likewise (t0b window).
__global__ __launch_bounds__(256) void gemm_win_k(
    const float* __restrict__ X,
    const float* __restrict__ Wf, const float* __restrict__ Wb,
    const float* __restrict__ bihf, const float* __restrict__ bhhf,
    const float* __restrict__ bihb, const float* __restrict__ bhhb,
    float* __restrict__ Gf, float* __restrict__ Gb, int phase)
{
  const int bx = blockIdx.x;   // 0..23: 0..11 fwd col tiles, 12..23 bwd
  const int by = blockIdx.y;   // batch 0..63
  const int tid = threadIdx.x;
  const int tx = tid & 15, ty = tid >> 4;
  const bool isb = (bx >= 12);
  const float* W = isb ? Wb : Wf;
  float* G = isb ? Gb : Gf;
  const int t0 = isb ? 128 * (1 - phase) : 128 * phase;
  const int n0d = (isb ? (bx - 12) : bx) * 128;

  __shared__ float As[16][132];
  __shared__ float Bs[16][132];

  float acc[8][8];
#pragma unroll
  for (int i = 0; i < 8; ++i)
#pragma unroll
    for (int j = 0; j < 8; ++j) acc[i][j] = 0.f;

  const int sr = tid >> 1;          // 0..127 (= tw for A, = col for B)
  const int sk = (tid & 1) * 8;
  const float* Xp = X + (size_t)(by * TT + t0 + sr) * HID + sk;
  const float* Wp = W + (size_t)(n0d + sr) * HID + sk;

  for (int k0 = 0; k0 < HID; k0 += 16) {
    float4 xa = *(const float4*)(Xp + k0);
    float4 xb = *(const float4*)(Xp + k0 + 4);
    float4 wa = *(const float4*)(Wp + k0);
    float4 wc = *(const float4*)(Wp + k0 + 4);
    __syncthreads();
    As[sk+0][sr] = xa.x; As[sk+1][sr] = xa.y; As[sk+2][sr] = xa.z; As[sk+3][sr] = xa.w;
    As[sk+4][sr] = xb.x; As[sk+5][sr] = xb.y; As[sk+6][sr] = xb.z; As[sk+7][sr] = xb.w;
    Bs[sk+0][sr] = wa.x; Bs[sk+1][sr] = wa.y; Bs[sk+2][sr] = wa.z; Bs[sk+3][sr] = wa.w;
    Bs[sk+4][sr] = wc.x; Bs[sk+5][sr] = wc.y; Bs[sk+6][sr] = wc.z; Bs[sk+7][sr] = wc.w;
    __syncthreads();
#pragma unroll
    for (int k = 0; k < 16; ++k) {
      float a[8], b[8];
      *(float4*)&a[0] = *(const float4*)&As[k][ty*4];
      *(float4*)&a[4] = *(const float4*)&As[k][64 + ty*4];
      *(float4*)&b[0] = *(const float4*)&Bs[k][tx*4];
      *(float4*)&b[4] = *(const float4*)&Bs[k][64 + tx*4];
#pragma unroll
      for (int i = 0; i < 8; ++i)
#pragma unroll
        for (int j = 0; j < 8; ++j)
          acc[i][j] += a[i] * b[j];
    }
  }

  const float* bi = isb ? bihb : bihf;
  const float* bh = isb ? bhhb : bhhf;
  float bias[8];
#pragma unroll
  for (int j = 0; j < 8; ++j) {
    int c = (j < 4) ? (tx*4 + j) : (64 + tx*4 + (j - 4));
    bias[j] = bi[n0d + c] + bh[n0d + c];
  }
#pragma unroll
  for (int i = 0; i < 8; ++i) {
    int rloc = (i < 4) ? (ty*4 + i) : (64 + ty*4 + (i - 4));   // tw
    size_t base = (size_t)(by * 128 + rloc) * 1536 + n0d;
    float4 v0, v1;
    v0.x = acc[i][0] + bias[0]; v0.y = acc[i][1] + bias[1];
    v0.z = acc[i][2] + bias[2]; v0.w = acc[i][3] + bias[3];
    v1.x = acc[i][4] + bias[4]; v1.y = acc[i][5] + bias[5];
    v1.z = acc[i][6] + bias[6]; v1.w = acc[i][7] + bias[7];
    *(float4*)(G + base + tx * 4) = v0;
    *(float4*)(G + base + 64 + tx * 4) = v1;
  }
}

// ======================= recurrent kernel (one 128-step phase) ==============
// 128 blocks = 2 dirs x 64; block owns 6 units (24 gate rows) x all 64 batch.
// Threads: b8=tid&7 (8 batches), r8=(tid>>3)&7 (3 rows), kz=tid>>6 (96-k seg).
// W_hh in LDS [24][388]; h[t-1] staged [k][b]. Layer 1 (emAcc!=null): fused FC.
__global__ __launch_bounds__(256) void rec_win_k(
    const float* __restrict__ whh_f, const float* __restrict__ whh_b,
    const float* __restrict__ Gf, const float* __restrict__ Gb,
    float* __restrict__ h_seq,      // layer0: [64][256][768]; layer1: unused
    float* __restrict__ h_cur,      // [2 dir][2 buf][384*64]
    float* __restrict__ c_cur,      // [2 dir][384*64]
    unsigned* __restrict__ cnt,     // [2 dir][8]
    int phase,
    float* __restrict__ emAcc,      // layer1: [16384][9] (+= h*fcw^T), else null
    const float* __restrict__ fcw)  // [9][768]
{
  const int d   = blockIdx.x >> 6;
  const int blk = blockIdx.x & 63;
  const int tid = threadIdx.x;
  const int u0  = blk * 6;
  const float* whh = d ? whh_b : whh_f;
  const float* Gd  = d ? Gb : Gf;
  const int t0 = d ? 128 * (1 - phase) : 128 * phase;
  unsigned* mycnt = cnt + d * 8;
  const bool fuseFC = (emAcc != nullptr);

  __shared__ float hT2[HHD * 64];     // 98304 B, [k][b]; tail reused as h_loc
  __shared__ float wlds[24][388];     // 37248 B
  __shared__ float red[4][24][68];    // 26112 B
  __shared__ float fcw_s[56];
  float* h_loc = hT2;                 // [6][64] alias, valid post-MAC only

  for (int r = 0; r < 24; ++r) {
    int grow = (r / 6) * HHD + u0 + (r % 6);
    for (int k = tid; k < HHD; k += 256)
      wlds[r][k] = whh[(size_t)grow * HHD + k];
  }
  if (fuseFC && tid < 54)
    fcw_s[tid] = fcw[(tid / 6) * HID + d * HHD + u0 + (tid % 6)];
  __syncthreads();

  const int b8 = tid & 7;
  const int r8 = (tid >> 3) & 7;
  const int kz = tid >> 6;

  // load carried c-state
  float cst[2] = {0.f, 0.f};
#pragma unroll
  for (int e = 0; e < 2; ++e) {
    int cidx = tid + e * 256;
    if (cidx < 384) {
      int un = cidx >> 6, b = cidx & 63;
      cst[e] = c_cur[(size_t)d * (HHD * 64) + (u0 + un) * 64 + b];
    }
  }

  const int ts0 = 128 * phase;
  for (int ts = ts0; ts < ts0 + 128; ++ts) {
    const int t = d ? (TT - 1 - ts) : ts;
    const int tw = t - t0;

    // prefetch input-projection gates for this step (G ready before launch)
    float gin[8];
#pragma unroll
    for (int e = 0; e < 2; ++e) {
      int cidx = tid + e * 256;
      int un = cidx >> 6, b = cidx & 63;
#pragma unroll
      for (int g = 0; g < 4; ++g) {
        if (cidx < 384)
          gin[e*4+g] = Gd[(size_t)(b * 128 + tw) * 1536 + g * HHD + u0 + un];
        else
          gin[e*4+g] = 0.f;
      }
    }

    if (ts > 0) {
      if (tid < 64) {
        const unsigned target = (unsigned)(8 * ts);
        long long tstart = clock64();
        while (true) {
          unsigned v = 0xFFFFFFFFu;
          if (tid < 8)
            v = __hip_atomic_load(&mycnt[tid], __ATOMIC_ACQUIRE, __HIP_MEMORY_SCOPE_AGENT);
          if (__all(v >= target)) break;
          if (clock64() - tstart > 200000000LL) break;  // fail loudly, not hang
          __builtin_amdgcn_s_sleep(2);
        }
      }
      __syncthreads();
    }

    // stage h[t-1] -> LDS
    const float* hsrc = h_cur + (size_t)(d * 2 + (ts & 1)) * (HHD * 64);
#pragma unroll
    for (int i = 0; i < 24; ++i) {
      int fi = (i * 256 + tid) * 4;
      *(float4*)&hT2[fi] = *(const float4*)(hsrc + fi);
    }
    __syncthreads();

    // MAC: C[3 rows][8 batches] over k in [kz*96, kz*96+96)
    float acc[3][8];
#pragma unroll
    for (int r = 0; r < 3; ++r)
#pragma unroll
      for (int b = 0; b < 8; ++b) acc[r][b] = 0.f;

    const int k0 = kz * 96;
#pragma unroll 2
    for (int q = 0; q < 24; ++q) {
      const int k = k0 + q * 4;
      float4 w0 = *(const float4*)&wlds[r8*3+0][k];
      float4 w1 = *(const float4*)&wlds[r8*3+1][k];
      float4 w2 = *(const float4*)&wlds[r8*3+2][k];
      const float wA[3][4] = {{w0.x,w0.y,w0.z,w0.w},
                              {w1.x,w1.y,w1.z,w1.w},
                              {w2.x,w2.y,w2.z,w2.w}};
#pragma unroll
      for (int j = 0; j < 4; ++j) {
        float4 hx = *(const float4*)&hT2[(k+j)*64 + b8*8];
        float4 hy = *(const float4*)&hT2[(k+j)*64 + b8*8 + 4];
        const float hv[8] = {hx.x,hx.y,hx.z,hx.w,hy.x,hy.y,hy.z,hy.w};
#pragma unroll
        for (int r = 0; r < 3; ++r)
#pragma unroll
          for (int b = 0; b < 8; ++b)
            acc[r][b] += wA[r][j] * hv[b];
      }
    }

#pragma unroll
    for (int r = 0; r < 3; ++r) {
      *(float4*)&red[kz][r8*3+r][b8*8]     = make_float4(acc[r][0], acc[r][1], acc[r][2], acc[r][3]);
      *(float4*)&red[kz][r8*3+r][b8*8 + 4] = make_float4(acc[r][4], acc[r][5], acc[r][6], acc[r][7]);
    }
    __syncthreads();

    // reduce + pointwise LSTM cell (gate order i,f,g,o)
    float* hdst = h_cur + (size_t)(d * 2 + ((ts + 1) & 1)) * (HHD * 64);
#pragma unroll
    for (int e = 0; e < 2; ++e) {
      int cidx = tid + e * 256;
      if (cidx < 384) {
        int un = cidx >> 6, b = cidx & 63;
        float gi = gin[e*4+0], gf = gin[e*4+1], gg = gin[e*4+2], go = gin[e*4+3];
#pragma unroll
        for (int z = 0; z < 4; ++z) {
          gi += red[z][0*6+un][b];
          gf += red[z][1*6+un][b];
          gg += red[z][2*6+un][b];
          go += red[z][3*6+un][b];
        }
        float ig = 1.f / (1.f + __expf(-gi));
        float fg = 1.f / (1.f + __expf(-gf));
        float gt = tanhf(gg);
        float og = 1.f / (1.f + __expf(-go));
        float c2 = fg * cst[e] + ig * gt;
        cst[e] = c2;
        float hvv = og * tanhf(c2);
        hdst[(u0 + un) * 64 + b] = hvv;
        if (!fuseFC) h_seq[((size_t)b * TT + t) * HID + d * HHD + u0 + un] = hvv;
        else h_loc[un * 64 + b] = hvv;   // hT2 dead post-MAC; safe alias
      }
    }

    if (fuseFC) {
      __syncthreads();
      if (tid < 64) {
        const int b = tid;
        float ev[9];
#pragma unroll
        for (int k = 0; k < 9; ++k) ev[k] = 0.f;
#pragma unroll
        for (int un = 0; un < 6; ++un) {
          float hv = h_loc[un * 64 + b];
#pragma unroll
          for (int k = 0; k < 9; ++k) ev[k] += hv * fcw_s[k * 6 + un];
        }
#pragma unroll
        for (int k = 0; k < 9; ++k)
          atomicAdd(&emAcc[(size_t)(b * TT + t) * 9 + k], ev[k]);
      }
    }

    __threadfence();
    __syncthreads();
    if (tid == 0)
      __hip_atomic_fetch_add(&mycnt[blk & 7], 1u, __ATOMIC_RELEASE, __HIP_MEMORY_SCOPE_AGENT);
  }

  // store carried c-state
#pragma unroll
  for (int e = 0; e < 2; ++e) {
    int cidx = tid + e * 256;
    if (cidx < 384) {
      int un = cidx >> 6, b = cidx & 63;
      c_cur[(size_t)d * (HHD * 64) + (u0 + un) * 64 + b] = cst[e];
    }
  }
}

// ======================= CRF loss + Viterbi (fp32 out) =======================
__global__ __launch_bounds__(64) void crf_k(
    const float* __restrict__ em, const float* __restrict__ fcb,
    const float* __restrict__ startt, const float* __restrict__ transt,
    const float* __restrict__ endt, const int* __restrict__ y,
    float* __restrict__ lossAcc, float* __restrict__ out)
{
  const int b = blockIdx.x, lane = threadIdx.x;
  __shared__ float ems[256][12];
  __shared__ float trs[9][12];
  __shared__ unsigned char hist[255][12];
  __shared__ int ytag[256];
  for (int i = lane; i < 2304; i += 64)
    ems[i / 9][i % 9] = em[(size_t)b * 2304 + i] + fcb[i % 9];
  for (int i = lane; i < 81; i += 64) trs[i / 9][i % 9] = transt[i];
  for (int i = lane; i < 256; i += 64) ytag[i] = y[b * 256 + i];
  __syncthreads();
  const int c = (lane < 9) ? lane : 0;
  float tcol[9];
#pragma unroll
  for (int p = 0; p < 9; ++p) tcol[p] = trs[p][c];
  float alpha = startt[c] + ems[0][c];
  float vsc = alpha;
  for (int t = 1; t < 256; ++t) {
    float ap[9], vp[9];
#pragma unroll
    for (int p = 0; p < 9; ++p) { ap[p] = __shfl(alpha, p); vp[p] = __shfl(vsc, p); }
    float mx = -1e30f, best = -1e30f; int arg = 0;
#pragma unroll
    for (int p = 0; p < 9; ++p) {
      float av = ap[p] + tcol[p];
      mx = fmaxf(mx, av);
      float vv = vp[p] + tcol[p];
      if (vv > best) { best = vv; arg = p; }   // strict >: first max (jnp.argmax)
    }
    float sm = 0.f;
#pragma unroll
    for (int p = 0; p < 9; ++p) sm += __expf(ap[p] + tcol[p] - mx);
    alpha = mx + __logf(sm) + ems[t][c];
    vsc = best + ems[t][c];
    if (lane < 9) hist[t - 1][c] = (unsigned char)arg;
  }
  float af = (lane < 9) ? (alpha + endt[c]) : -1e30f;
  float vf = (lane < 9) ? (vsc + endt[c]) : -1e30f;
  float a2[9], v2[9];
#pragma unroll
  for (int p = 0; p < 9; ++p) { a2[p] = __shfl(af, p); v2[p] = __shfl(vf, p); }
  float mm = -1e30f;
#pragma unroll
  for (int p = 0; p < 9; ++p) mm = fmaxf(mm, a2[p]);
  float ss = 0.f;
#pragma unroll
  for (int p = 0; p < 9; ++p) ss += __expf(a2[p] - mm);
  float den = mm + __logf(ss);
  int last = 0; float bb2 = -1e30f;
#pragma unroll
  for (int p = 0; p < 9; ++p) if (v2[p] > bb2) { bb2 = v2[p]; last = p; }
  float np = 0.f;
  for (int t = lane; t < 256; t += 64) np += ems[t][ytag[t]];
  for (int t = lane; t < 255; t += 64) np += trs[ytag[t]][ytag[t + 1]];
#pragma unroll
  for (int off = 32; off > 0; off >>= 1) np += __shfl_down(np, off);
  if (lane == 0) {
    float num = np + startt[ytag[0]] + endt[ytag[255]];
    atomicAdd(lossAcc, num - den);
    int tg = last;
    out[1 + b * 256 + 255] = (float)tg;
    for (int t = 254; t >= 0; --t) {
      tg = hist[t][tg];
      out[1 + b * 256 + t] = (float)tg;
    }
  }
}

__global__ void fin_k(const float* __restrict__ lossAcc, float* __restrict__ out)
{
  if (threadIdx.x == 0 && blockIdx.x == 0) out[0] = lossAcc[0];
}

// ======================= launch =======================
extern "C" void kernel_launch(void* const* d_in, const int* in_sizes, int n_in,
                              void* d_out, int out_size, void* d_ws, size_t ws_size,
                              hipStream_t stream)
{
  const float* bert  = (const float*)d_in[0];
  const float* wih0f = (const float*)d_in[1];
  const float* whh0f = (const float*)d_in[2];
  const float* bih0f = (const float*)d_in[3];
  const float* bhh0f = (const float*)d_in[4];
  const float* wih0b = (const float*)d_in[5];
  const float* whh0b = (const float*)d_in[6];
  const float* bih0b = (const float*)d_in[7];
  const float* bhh0b = (const float*)d_in[8];
  const float* wih1f = (const float*)d_in[9];
  const float* whh1f = (const float*)d_in[10];
  const float* bih1f = (const float*)d_in[11];
  const float* bhh1f = (const float*)d_in[12];
  const float* wih1b = (const float*)d_in[13];
  const float* whh1b = (const float*)d_in[14];
  const float* bih1b = (const float*)d_in[15];
  const float* bhh1b = (const float*)d_in[16];
  const float* fcw   = (const float*)d_in[17];
  const float* fcb   = (const float*)d_in[18];
  const float* stt   = (const float*)d_in[19];
  const float* trn   = (const float*)d_in[20];
  const float* ent   = (const float*)d_in[21];
  const int*   y     = (const int*)d_in[22];

  // workspace layout (float offsets); total 38,043,684 fl = 152.2 MB
  float* W = (float*)d_ws;
  unsigned* cnt  = (unsigned*)d_ws;            // 32 u32 (2 layers x 2 dirs x 8)
  float* lossAcc = W + 32;
  float* hc      = W + 36;                     // 2*2*384*64 = 98304
  float* cc      = W + 98340;                  // 2*384*64   = 49152
  float* em      = W + 147492;                 // 16384*9    = 147456
  float* h       = W + 294948;                 // 16384*768  = 12582912
  float* Gf      = W + 12877860;               // 64*128*1536
  float* Gb      = W + 25460772;               // 64*128*1536

  // zero cnt/loss/hc/cc/em
  hipMemsetAsync(d_ws, 0, (size_t)294948 * 4, stream);

  dim3 ggrid(24, 64);
  // ---- layer 0 (writes h) ----
  gemm_win_k<<<ggrid, 256, 0, stream>>>(bert, wih0f, wih0b, bih0f, bhh0f, bih0b, bhh0b, Gf, Gb, 0);
  rec_win_k<<<128, 256, 0, stream>>>(whh0f, whh0b, Gf, Gb, h, hc, cc, cnt, 0, nullptr, nullptr);
  gemm_win_k<<<ggrid, 256, 0, stream>>>(bert, wih0f, wih0b, bih0f, bhh0f, bih0b, bhh0b, Gf, Gb, 1);
  rec_win_k<<<128, 256, 0, stream>>>(whh0f, whh0b, Gf, Gb, h, hc, cc, cnt, 1, nullptr, nullptr);
  // reset h/c carry state for layer 1
  hipMemsetAsync((void*)hc, 0, (size_t)(98304 + 49152) * 4, stream);
  // ---- layer 1 (fused FC -> em) ----
  gemm_win_k<<<ggrid, 256, 0, stream>>>(h, wih1f, wih1b, bih1f, bhh1f, bih1b, bhh1b, Gf, Gb, 0);
  rec_win_k<<<128, 256, 0, stream>>>(whh1f, whh1b, Gf, Gb, nullptr, hc, cc, cnt + 16, 0, em, fcw);
  gemm_win_k<<<ggrid, 256, 0, stream>>>(h, wih1f, wih1b, bih1f, bhh1f, bih1b, bhh1b, Gf, Gb, 1);
  rec_win_k<<<128, 256, 0, stream>>>(whh1f, whh1b, Gf, Gb, nullptr, hc, cc, cnt + 16, 1, em, fcw);
  // ---- CRF + Viterbi ----
  crf_k<<<64, 64, 0, stream>>>(em, fcb, stt, trn, ent, y, lossAcc, (float*)d_out);
  fin_k<<<1, 64, 0, stream>>>(lossAcc, (float*)d_out);
}

// Round 7
// 10307.080 us; speedup vs baseline: 1.5670x; 1.5670x over previous
//
#include <hip/hip_runtime.h>
#include <math.h>

// ---------------------------------------------------------------------------
// bert_output -> 2-layer BiLSTM -> FC -> CRF(loss) + Viterbi(tags)
// B=64 T=256 H=768 HH=384 K=9.  d_out is FLOAT32: [loss, tags(16384)].
// Windowed pipeline per layer: {gemm(win A); rec(128 steps); gemm(win B);
// rec(128 steps)} so the fp32 gate buffer is 2x50.3MB instead of 201MB.
// Layer 1's rec fuses the FC (em accumulation); fc bias added in crf_k.
// r4: inter-block sync rebuilt on RELAXED agent-scope atomics (no
// threadfence/ACQUIRE -> no per-step L2 writeback/invalidate storms).
// r6 = r4 with watchdog 200M->20M cycles (hedge vs container-kill).
// r7 = r6 resubmitted verbatim: r4/r5/r6 benches were all infra failures
// (acquisition timeout / container failure); the kernel has never run.
// ---------------------------------------------------------------------------

#define TT 256
#define HID 768
#define HHD 384

#define AL(p)    __hip_atomic_load((p), __ATOMIC_RELAXED, __HIP_MEMORY_SCOPE_AGENT)
#define AS(p, v) __hip_atomic_store((p), (v), __ATOMIC_RELAXED, __HIP_MEMORY_SCOPE_AGENT)

// ======================= windowed input GEMM =======================
// Gf[b][tw][1536] <- X[b][t0f+tw] @ Wf^T + bias ; Gb likewise (t0b window).
__global__ __launch_bounds__(256) void gemm_win_k(
    const float* __restrict__ X,
    const float* __restrict__ Wf, const float* __restrict__ Wb,
    const float* __restrict__ bihf, const float* __restrict__ bhhf,
    const float* __restrict__ bihb, const float* __restrict__ bhhb,
    float* __restrict__ Gf, float* __restrict__ Gb, int phase)
{
  const int bx = blockIdx.x;   // 0..23: 0..11 fwd col tiles, 12..23 bwd
  const int by = blockIdx.y;   // batch 0..63
  const int tid = threadIdx.x;
  const int tx = tid & 15, ty = tid >> 4;
  const bool isb = (bx >= 12);
  const float* W = isb ? Wb : Wf;
  float* G = isb ? Gb : Gf;
  const int t0 = isb ? 128 * (1 - phase) : 128 * phase;
  const int n0d = (isb ? (bx - 12) : bx) * 128;

  __shared__ float As[16][132];
  __shared__ float Bs[16][132];

  float acc[8][8];
#pragma unroll
  for (int i = 0; i < 8; ++i)
#pragma unroll
    for (int j = 0; j < 8; ++j) acc[i][j] = 0.f;

  const int sr = tid >> 1;          // 0..127 (= tw for A, = col for B)
  const int sk = (tid & 1) * 8;
  const float* Xp = X + (size_t)(by * TT + t0 + sr) * HID + sk;
  const float* Wp = W + (size_t)(n0d + sr) * HID + sk;

  for (int k0 = 0; k0 < HID; k0 += 16) {
    float4 xa = *(const float4*)(Xp + k0);
    float4 xb = *(const float4*)(Xp + k0 + 4);
    float4 wa = *(const float4*)(Wp + k0);
    float4 wc = *(const float4*)(Wp + k0 + 4);
    __syncthreads();
    As[sk+0][sr] = xa.x; As[sk+1][sr] = xa.y; As[sk+2][sr] = xa.z; As[sk+3][sr] = xa.w;
    As[sk+4][sr] = xb.x; As[sk+5][sr] = xb.y; As[sk+6][sr] = xb.z; As[sk+7][sr] = xb.w;
    Bs[sk+0][sr] = wa.x; Bs[sk+1][sr] = wa.y; Bs[sk+2][sr] = wa.z; Bs[sk+3][sr] = wa.w;
    Bs[sk+4][sr] = wc.x; Bs[sk+5][sr] = wc.y; Bs[sk+6][sr] = wc.z; Bs[sk+7][sr] = wc.w;
    __syncthreads();
#pragma unroll
    for (int k = 0; k < 16; ++k) {
      float a[8], b[8];
      *(float4*)&a[0] = *(const float4*)&As[k][ty*4];
      *(float4*)&a[4] = *(const float4*)&As[k][64 + ty*4];
      *(float4*)&b[0] = *(const float4*)&Bs[k][tx*4];
      *(float4*)&b[4] = *(const float4*)&Bs[k][64 + tx*4];
#pragma unroll
      for (int i = 0; i < 8; ++i)
#pragma unroll
        for (int j = 0; j < 8; ++j)
          acc[i][j] += a[i] * b[j];
    }
  }

  const float* bi = isb ? bihb : bihf;
  const float* bh = isb ? bhhb : bhhf;
  float bias[8];
#pragma unroll
  for (int j = 0; j < 8; ++j) {
    int c = (j < 4) ? (tx*4 + j) : (64 + tx*4 + (j - 4));
    bias[j] = bi[n0d + c] + bh[n0d + c];
  }
#pragma unroll
  for (int i = 0; i < 8; ++i) {
    int rloc = (i < 4) ? (ty*4 + i) : (64 + ty*4 + (i - 4));   // tw
    size_t base = (size_t)(by * 128 + rloc) * 1536 + n0d;
    float4 v0, v1;
    v0.x = acc[i][0] + bias[0]; v0.y = acc[i][1] + bias[1];
    v0.z = acc[i][2] + bias[2]; v0.w = acc[i][3] + bias[3];
    v1.x = acc[i][4] + bias[4]; v1.y = acc[i][5] + bias[5];
    v1.z = acc[i][6] + bias[6]; v1.w = acc[i][7] + bias[7];
    *(float4*)(G + base + tx * 4) = v0;
    *(float4*)(G + base + 64 + tx * 4) = v1;
  }
}

// ======================= recurrent kernel (one 128-step phase) ==============
// 128 blocks = 2 dirs x 64; block owns 6 units (24 gate rows) x all 64 batch.
// Threads: b8=tid&7 (8 batches), r8=(tid>>3)&7 (3 rows), kz=tid>>6 (96-k seg).
// W_hh in LDS [24][388]; h[t-1] staged [k][b]. Layer 1 (emAcc!=null): fused FC.
// Sync: h via RELAXED agent atomics (L2-bypass, MALL-coherent); ordering via
// __syncthreads' vmcnt(0) drain; counters RELAXED add / RELAXED poll.
__global__ __launch_bounds__(256) void rec_win_k(
    const float* __restrict__ whh_f, const float* __restrict__ whh_b,
    const float* __restrict__ Gf, const float* __restrict__ Gb,
    float* __restrict__ h_seq,      // layer0: [64][256][768]; layer1: unused
    float* __restrict__ h_cur,      // [2 dir][2 buf][384*64]
    float* __restrict__ c_cur,      // [2 dir][384*64]
    unsigned* __restrict__ cnt,     // [2 dir][8]
    int phase,
    float* __restrict__ emAcc,      // layer1: [16384][9] (+= h*fcw^T), else null
    const float* __restrict__ fcw)  // [9][768]
{
  const int d   = blockIdx.x >> 6;
  const int blk = blockIdx.x & 63;
  const int tid = threadIdx.x;
  const int u0  = blk * 6;
  const float* whh = d ? whh_b : whh_f;
  const float* Gd  = d ? Gb : Gf;
  const int t0 = d ? 128 * (1 - phase) : 128 * phase;
  unsigned* mycnt = cnt + d * 8;
  const bool fuseFC = (emAcc != nullptr);

  __shared__ float hT2[HHD * 64];     // 98304 B, [k][b]; tail reused as h_loc
  __shared__ float wlds[24][388];     // 37248 B
  __shared__ float red[4][24][68];    // 26112 B
  __shared__ float fcw_s[56];
  float* h_loc = hT2;                 // [6][64] alias, valid post-MAC only

  for (int r = 0; r < 24; ++r) {
    int grow = (r / 6) * HHD + u0 + (r % 6);
    for (int k = tid; k < HHD; k += 256)
      wlds[r][k] = whh[(size_t)grow * HHD + k];
  }
  if (fuseFC && tid < 54)
    fcw_s[tid] = fcw[(tid / 6) * HID + d * HHD + u0 + (tid % 6)];
  __syncthreads();

  const int b8 = tid & 7;
  const int r8 = (tid >> 3) & 7;
  const int kz = tid >> 6;

  // load carried c-state
  float cst[2] = {0.f, 0.f};
#pragma unroll
  for (int e = 0; e < 2; ++e) {
    int cidx = tid + e * 256;
    if (cidx < 384) {
      int un = cidx >> 6, b = cidx & 63;
      cst[e] = c_cur[(size_t)d * (HHD * 64) + (u0 + un) * 64 + b];
    }
  }

  const int ts0 = 128 * phase;
  for (int ts = ts0; ts < ts0 + 128; ++ts) {
    const int t = d ? (TT - 1 - ts) : ts;
    const int tw = t - t0;

    // prefetch input-projection gates for this step (G ready before launch)
    float gin[8];
#pragma unroll
    for (int e = 0; e < 2; ++e) {
      int cidx = tid + e * 256;
      int un = cidx >> 6, b = cidx & 63;
#pragma unroll
      for (int g = 0; g < 4; ++g) {
        if (cidx < 384)
          gin[e*4+g] = Gd[(size_t)(b * 128 + tw) * 1536 + g * HHD + u0 + un];
        else
          gin[e*4+g] = 0.f;
      }
    }

    if (ts > 0 && tid < 64) {
      const unsigned target = (unsigned)(8 * ts);
      long long tstart = clock64();
      while (true) {
        unsigned v = 0xFFFFFFFFu;
        if (tid < 8) v = AL(&mycnt[tid]);
        if (__all(v >= target)) break;
        if (clock64() - tstart > 20000000LL) break;  // ~8ms: fail loudly, not hang
        __builtin_amdgcn_s_sleep(1);
      }
    }
    __syncthreads();                                  // (A)

    // stage h[t-1] -> LDS via L2-bypass loads
    const float* hsrc = h_cur + (size_t)(d * 2 + (ts & 1)) * (HHD * 64);
#pragma unroll
    for (int i = 0; i < 24; ++i) {
      int fi = (i * 256 + tid) * 4;
      float4 v;
      v.x = AL((float*)(hsrc + fi + 0));
      v.y = AL((float*)(hsrc + fi + 1));
      v.z = AL((float*)(hsrc + fi + 2));
      v.w = AL((float*)(hsrc + fi + 3));
      *(float4*)&hT2[fi] = v;
    }
    __syncthreads();                                  // (B)

    // MAC: C[3 rows][8 batches] over k in [kz*96, kz*96+96)
    float acc[3][8];
#pragma unroll
    for (int r = 0; r < 3; ++r)
#pragma unroll
      for (int b = 0; b < 8; ++b) acc[r][b] = 0.f;

    const int k0 = kz * 96;
#pragma unroll 2
    for (int q = 0; q < 24; ++q) {
      const int k = k0 + q * 4;
      float4 w0 = *(const float4*)&wlds[r8*3+0][k];
      float4 w1 = *(const float4*)&wlds[r8*3+1][k];
      float4 w2 = *(const float4*)&wlds[r8*3+2][k];
      const float wA[3][4] = {{w0.x,w0.y,w0.z,w0.w},
                              {w1.x,w1.y,w1.z,w1.w},
                              {w2.x,w2.y,w2.z,w2.w}};
#pragma unroll
      for (int j = 0; j < 4; ++j) {
        float4 hx = *(const float4*)&hT2[(k+j)*64 + b8*8];
        float4 hy = *(const float4*)&hT2[(k+j)*64 + b8*8 + 4];
        const float hv[8] = {hx.x,hx.y,hx.z,hx.w,hy.x,hy.y,hy.z,hy.w};
#pragma unroll
        for (int r = 0; r < 3; ++r)
#pragma unroll
          for (int b = 0; b < 8; ++b)
            acc[r][b] += wA[r][j] * hv[b];
      }
    }

#pragma unroll
    for (int r = 0; r < 3; ++r) {
      *(float4*)&red[kz][r8*3+r][b8*8]     = make_float4(acc[r][0], acc[r][1], acc[r][2], acc[r][3]);
      *(float4*)&red[kz][r8*3+r][b8*8 + 4] = make_float4(acc[r][4], acc[r][5], acc[r][6], acc[r][7]);
    }
    __syncthreads();                                  // (C)

    // reduce + pointwise LSTM cell (gate order i,f,g,o)
    float* hdst = h_cur + (size_t)(d * 2 + ((ts + 1) & 1)) * (HHD * 64);
#pragma unroll
    for (int e = 0; e < 2; ++e) {
      int cidx = tid + e * 256;
      if (cidx < 384) {
        int un = cidx >> 6, b = cidx & 63;
        float gi = gin[e*4+0], gf = gin[e*4+1], gg = gin[e*4+2], go = gin[e*4+3];
#pragma unroll
        for (int z = 0; z < 4; ++z) {
          gi += red[z][0*6+un][b];
          gf += red[z][1*6+un][b];
          gg += red[z][2*6+un][b];
          go += red[z][3*6+un][b];
        }
        float ig = 1.f / (1.f + __expf(-gi));
        float fg = 1.f / (1.f + __expf(-gf));
        float gt = tanhf(gg);
        float og = 1.f / (1.f + __expf(-go));
        float c2 = fg * cst[e] + ig * gt;
        cst[e] = c2;
        float hvv = og * tanhf(c2);
        AS(&hdst[(u0 + un) * 64 + b], hvv);           // L2-bypass publish
        if (!fuseFC) h_seq[((size_t)b * TT + t) * HID + d * HHD + u0 + un] = hvv;
        else h_loc[un * 64 + b] = hvv;   // hT2 dead post-MAC; safe alias
      }
    }
    __syncthreads();   // (D): drains every wave's vmcnt -> h stores complete
    if (tid == 0)
      __hip_atomic_fetch_add(&mycnt[blk & 7], 1u, __ATOMIC_RELAXED, __HIP_MEMORY_SCOPE_AGENT);

    // fused FC on wave 1, overlapping wave 0's next-step poll
    if (fuseFC && tid >= 64 && tid < 128) {
      const int b = tid - 64;
      float ev[9];
#pragma unroll
      for (int k = 0; k < 9; ++k) ev[k] = 0.f;
#pragma unroll
      for (int un = 0; un < 6; ++un) {
        float hv = h_loc[un * 64 + b];
#pragma unroll
        for (int k = 0; k < 9; ++k) ev[k] += hv * fcw_s[k * 6 + un];
      }
#pragma unroll
      for (int k = 0; k < 9; ++k)
        atomicAdd(&emAcc[(size_t)(b * TT + t) * 9 + k], ev[k]);
    }
  }

  // store carried c-state
#pragma unroll
  for (int e = 0; e < 2; ++e) {
    int cidx = tid + e * 256;
    if (cidx < 384) {
      int un = cidx >> 6, b = cidx & 63;
      c_cur[(size_t)d * (HHD * 64) + (u0 + un) * 64 + b] = cst[e];
    }
  }
}

// ======================= CRF loss + Viterbi (fp32 out) =======================
__global__ __launch_bounds__(64) void crf_k(
    const float* __restrict__ em, const float* __restrict__ fcb,
    const float* __restrict__ startt, const float* __restrict__ transt,
    const float* __restrict__ endt, const int* __restrict__ y,
    float* __restrict__ lossAcc, float* __restrict__ out)
{
  const int b = blockIdx.x, lane = threadIdx.x;
  __shared__ float ems[256][12];
  __shared__ float trs[9][12];
  __shared__ unsigned char hist[255][12];
  __shared__ int ytag[256];
  for (int i = lane; i < 2304; i += 64)
    ems[i / 9][i % 9] = em[(size_t)b * 2304 + i] + fcb[i % 9];
  for (int i = lane; i < 81; i += 64) trs[i / 9][i % 9] = transt[i];
  for (int i = lane; i < 256; i += 64) ytag[i] = y[b * 256 + i];
  __syncthreads();
  const int c = (lane < 9) ? lane : 0;
  float tcol[9];
#pragma unroll
  for (int p = 0; p < 9; ++p) tcol[p] = trs[p][c];
  float alpha = startt[c] + ems[0][c];
  float vsc = alpha;
  for (int t = 1; t < 256; ++t) {
    float ap[9], vp[9];
#pragma unroll
    for (int p = 0; p < 9; ++p) { ap[p] = __shfl(alpha, p); vp[p] = __shfl(vsc, p); }
    float mx = -1e30f, best = -1e30f; int arg = 0;
#pragma unroll
    for (int p = 0; p < 9; ++p) {
      float av = ap[p] + tcol[p];
      mx = fmaxf(mx, av);
      float vv = vp[p] + tcol[p];
      if (vv > best) { best = vv; arg = p; }   // strict >: first max (jnp.argmax)
    }
    float sm = 0.f;
#pragma unroll
    for (int p = 0; p < 9; ++p) sm += __expf(ap[p] + tcol[p] - mx);
    alpha = mx + __logf(sm) + ems[t][c];
    vsc = best + ems[t][c];
    if (lane < 9) hist[t - 1][c] = (unsigned char)arg;
  }
  float af = (lane < 9) ? (alpha + endt[c]) : -1e30f;
  float vf = (lane < 9) ? (vsc + endt[c]) : -1e30f;
  float a2[9], v2[9];
#pragma unroll
  for (int p = 0; p < 9; ++p) { a2[p] = __shfl(af, p); v2[p] = __shfl(vf, p); }
  float mm = -1e30f;
#pragma unroll
  for (int p = 0; p < 9; ++p) mm = fmaxf(mm, a2[p]);
  float ss = 0.f;
#pragma unroll
  for (int p = 0; p < 9; ++p) ss += __expf(a2[p] - mm);
  float den = mm + __logf(ss);
  int last = 0; float bb2 = -1e30f;
#pragma unroll
  for (int p = 0; p < 9; ++p) if (v2[p] > bb2) { bb2 = v2[p]; last = p; }
  float np = 0.f;
  for (int t = lane; t < 256; t += 64) np += ems[t][ytag[t]];
  for (int t = lane; t < 255; t += 64) np += trs[ytag[t]][ytag[t + 1]];
#pragma unroll
  for (int off = 32; off > 0; off >>= 1) np += __shfl_down(np, off);
  if (lane == 0) {
    float num = np + startt[ytag[0]] + endt[ytag[255]];
    atomicAdd(lossAcc, num - den);
    int tg = last;
    out[1 + b * 256 + 255] = (float)tg;
    for (int t = 254; t >= 0; --t) {
      tg = hist[t][tg];
      out[1 + b * 256 + t] = (float)tg;
    }
  }
}

__global__ void fin_k(const float* __restrict__ lossAcc, float* __restrict__ out)
{
  if (threadIdx.x == 0 && blockIdx.x == 0) out[0] = lossAcc[0];
}

// ======================= launch =======================
extern "C" void kernel_launch(void* const* d_in, const int* in_sizes, int n_in,
                              void* d_out, int out_size, void* d_ws, size_t ws_size,
                              hipStream_t stream)
{
  const float* bert  = (const float*)d_in[0];
  const float* wih0f = (const float*)d_in[1];
  const float* whh0f = (const float*)d_in[2];
  const float* bih0f = (const float*)d_in[3];
  const float* bhh0f = (const float*)d_in[4];
  const float* wih0b = (const float*)d_in[5];
  const float* whh0b = (const float*)d_in[6];
  const float* bih0b = (const float*)d_in[7];
  const float* bhh0b = (const float*)d_in[8];
  const float* wih1f = (const float*)d_in[9];
  const float* whh1f = (const float*)d_in[10];
  const float* bih1f = (const float*)d_in[11];
  const float* bhh1f = (const float*)d_in[12];
  const float* wih1b = (const float*)d_in[13];
  const float* whh1b = (const float*)d_in[14];
  const float* bih1b = (const float*)d_in[15];
  const float* bhh1b = (const float*)d_in[16];
  const float* fcw   = (const float*)d_in[17];
  const float* fcb   = (const float*)d_in[18];
  const float* stt   = (const float*)d_in[19];
  const float* trn   = (const float*)d_in[20];
  const float* ent   = (const float*)d_in[21];
  const int*   y     = (const int*)d_in[22];

  // workspace layout (float offsets); total 38,043,684 fl = 152.2 MB
  float* W = (float*)d_ws;
  unsigned* cnt  = (unsigned*)d_ws;            // 32 u32 (2 layers x 2 dirs x 8)
  float* lossAcc = W + 32;
  float* hc      = W + 36;                     // 2*2*384*64 = 98304
  float* cc      = W + 98340;                  // 2*384*64   = 49152
  float* em      = W + 147492;                 // 16384*9    = 147456
  float* h       = W + 294948;                 // 16384*768  = 12582912
  float* Gf      = W + 12877860;               // 64*128*1536
  float* Gb      = W + 25460772;               // 64*128*1536

  // zero cnt/loss/hc/cc/em
  hipMemsetAsync(d_ws, 0, (size_t)294948 * 4, stream);

  dim3 ggrid(24, 64);
  // ---- layer 0 (writes h) ----
  gemm_win_k<<<ggrid, 256, 0, stream>>>(bert, wih0f, wih0b, bih0f, bhh0f, bih0b, bhh0b, Gf, Gb, 0);
  rec_win_k<<<128, 256, 0, stream>>>(whh0f, whh0b, Gf, Gb, h, hc, cc, cnt, 0, nullptr, nullptr);
  gemm_win_k<<<ggrid, 256, 0, stream>>>(bert, wih0f, wih0b, bih0f, bhh0f, bih0b, bhh0b, Gf, Gb, 1);
  rec_win_k<<<128, 256, 0, stream>>>(whh0f, whh0b, Gf, Gb, h, hc, cc, cnt, 1, nullptr, nullptr);
  // reset h/c carry state for layer 1
  hipMemsetAsync((void*)hc, 0, (size_t)(98304 + 49152) * 4, stream);
  // ---- layer 1 (fused FC -> em) ----
  gemm_win_k<<<ggrid, 256, 0, stream>>>(h, wih1f, wih1b, bih1f, bhh1f, bih1b, bhh1b, Gf, Gb, 0);
  rec_win_k<<<128, 256, 0, stream>>>(whh1f, whh1b, Gf, Gb, nullptr, hc, cc, cnt + 16, 0, em, fcw);
  gemm_win_k<<<ggrid, 256, 0, stream>>>(h, wih1f, wih1b, bih1f, bhh1f, bih1b, bhh1b, Gf, Gb, 1);
  rec_win_k<<<128, 256, 0, stream>>>(whh1f, whh1b, Gf, Gb, nullptr, hc, cc, cnt + 16, 1, em, fcw);
  // ---- CRF + Viterbi ----
  crf_k<<<64, 64, 0, stream>>>(em, fcb, stt, trn, ent, y, lossAcc, (float*)d_out);
  fin_k<<<1, 64, 0, stream>>>(lossAcc, (float*)d_out);
}